// Round 6
// baseline (2011.859 us; speedup 1.0000x reference)
//
#include <hip/hip_runtime.h>
#include <cstddef>

namespace {

typedef _Float16 half_t;
typedef _Float16 half2_t __attribute__((ext_vector_type(2)));
typedef _Float16 f16x4 __attribute__((ext_vector_type(4)));
typedef _Float16 f16x8 __attribute__((ext_vector_type(8)));
typedef float f32x4 __attribute__((ext_vector_type(4)));

constexpr int NB = 256;  // batch
constexpr int NT = 512;  // time
constexpr int NH = 128;  // hidden
constexpr int NG = 512;  // 4*NH gates

__device__ __forceinline__ float sigm(float x) { return 1.0f / (1.0f + __expf(-x)); }
__device__ __forceinline__ float tanh_(float x) { return 2.0f / (1.0f + __expf(-2.0f * x)) - 1.0f; }
__device__ __forceinline__ float dot4(float4 w, float4 v, float acc) {
  return fmaf(w.x, v.x, fmaf(w.y, v.y, fmaf(w.z, v.z, fmaf(w.w, v.w, acc))));
}
__device__ __forceinline__ float fdot2(half2_t a, half2_t b, float c) {
  return __builtin_amdgcn_fdot2(a, b, c, false);  // v_dot2_f32_f16, f32 accum
}
__device__ __forceinline__ half2_t lo2(f16x8 v, int q) {  // extract pair q (0..3)
  half2_t r; r[0] = v[2 * q]; r[1] = v[2 * q + 1]; return r;
}
__device__ __forceinline__ void pinv8(f16x8& x) { asm volatile("" : "+v"(x)); }

// fp32 -> fp16 conversion (Whh prep)
__global__ void cvt_kernel(const float* __restrict__ s, half_t* __restrict__ d, int n4) {
  int i = blockIdx.x * blockDim.x + threadIdx.x;
  if (i < n4) {
    float4 v = reinterpret_cast<const float4*>(s)[i];
    f16x4 hv = {(half_t)v.x, (half_t)v.y, (half_t)v.z, (half_t)v.w};
    reinterpret_cast<f16x4*>(d)[i] = hv;
  }
}

// ============ MFMA GEMM: C[M,Nstr tile] = A[M,K] * B[N,K]^T + b0 + b1 ============
// BM=128, BN=64, 256 threads = 4 waves (each wave: 32 rows x 64 cols, 2x4 frags).
template <int K, bool AF32, bool F32OUT>
__global__ __launch_bounds__(256) void xg_gemm(
    const void* __restrict__ Ap, const float* __restrict__ Bw,
    const float* __restrict__ b0, const float* __restrict__ b1,
    half_t* __restrict__ Ch, float* __restrict__ Cf, int Nstr)
{
  __shared__ __align__(16) half_t Atile[128 * K];
  __shared__ __align__(16) half_t Btile[64 * K];
  const int tid = threadIdx.x;
  const int m0 = blockIdx.x * 128;
  const int n0 = blockIdx.y * 64;
  char* Ab = (char*)Atile;
  char* Bb = (char*)Btile;

  if (AF32) {
    const float* Af = (const float*)Ap;
    for (int idx = tid; idx < 128 * K / 4; idx += 256) {
      int row = idx / (K / 4), o = idx % (K / 4);
      float4 v = *(const float4*)(Af + (size_t)(m0 + row) * K + 4 * o);
      f16x4 hv = {(half_t)v.x, (half_t)v.y, (half_t)v.z, (half_t)v.w};
      int byte = ((row * K + 4 * o) * 2) ^ ((row & 7) << 4);
      *(f16x4*)(Ab + byte) = hv;
    }
  } else {
    const half_t* Ah = (const half_t*)Ap;
    for (int idx = tid; idx < 128 * K / 8; idx += 256) {
      int row = idx / (K / 8), o = idx % (K / 8);
      uint4 v = *(const uint4*)(Ah + (size_t)(m0 + row) * K + 8 * o);
      int byte = ((row * K + 8 * o) * 2) ^ ((row & 7) << 4);
      *(uint4*)(Ab + byte) = v;
    }
  }
  for (int idx = tid; idx < 64 * K / 4; idx += 256) {
    int row = idx / (K / 4), o = idx % (K / 4);
    float4 v = *(const float4*)(Bw + (size_t)(n0 + row) * K + 4 * o);
    f16x4 hv = {(half_t)v.x, (half_t)v.y, (half_t)v.z, (half_t)v.w};
    int byte = ((row * K + 4 * o) * 2) ^ ((row & 7) << 4);
    *(f16x4*)(Bb + byte) = hv;
  }
  __syncthreads();

  const int lane = tid & 63, w = tid >> 6;
  const int r16 = lane & 15, koff = (lane >> 4) * 8;
  f32x4 acc[2][4];
#pragma unroll
  for (int fm = 0; fm < 2; ++fm)
#pragma unroll
    for (int fn = 0; fn < 4; ++fn) acc[fm][fn] = (f32x4){0.f, 0.f, 0.f, 0.f};

#pragma unroll
  for (int ks = 0; ks < K / 32; ++ks) {
    f16x8 a[2], bf[4];
#pragma unroll
    for (int fm = 0; fm < 2; ++fm) {
      int row = w * 32 + fm * 16 + r16;
      int byte = ((row * K + ks * 32 + koff) * 2) ^ ((row & 7) << 4);
      a[fm] = *(const f16x8*)(Ab + byte);
    }
#pragma unroll
    for (int fn = 0; fn < 4; ++fn) {
      int row = fn * 16 + r16;
      int byte = ((row * K + ks * 32 + koff) * 2) ^ ((row & 7) << 4);
      bf[fn] = *(const f16x8*)(Bb + byte);
    }
#pragma unroll
    for (int fm = 0; fm < 2; ++fm)
#pragma unroll
      for (int fn = 0; fn < 4; ++fn)
        acc[fm][fn] = __builtin_amdgcn_mfma_f32_16x16x32_f16(a[fm], bf[fn], acc[fm][fn], 0, 0, 0);
  }

  // D layout: col = lane&15, row = (lane>>4)*4 + q
#pragma unroll
  for (int fm = 0; fm < 2; ++fm)
#pragma unroll
    for (int fn = 0; fn < 4; ++fn) {
      int n = n0 + fn * 16 + r16;
      float bb = (b0 ? b0[n] : 0.f) + (b1 ? b1[n] : 0.f);
#pragma unroll
      for (int q = 0; q < 4; ++q) {
        int m = m0 + w * 32 + fm * 16 + (lane >> 4) * 4 + q;
        float val = acc[fm][fn][q] + bb;
        if (F32OUT) Cf[(size_t)m * Nstr + n] = val;
        else        Ch[(size_t)m * Nstr + n] = (half_t)val;
      }
    }
}

// ============ Recurrent kernel (slim: xg precomputed) ============
// MODE: 0 = xg-stream -> seq-out (enc0, dec1)
//       1 = xg-stream -> hT-out  (enc1)
//       2 = const-xg  -> seq-out (dec0; xg from hT_in, computed once)
// One block per batch element, 512 threads (8 waves = 2/SIMD).
// amdgpu_waves_per_eu(2,2): VGPR budget 256 so the pinned Whh fragment (64
// regs) stays resident -- launch_bounds(512,2)'s min-blocks second arg capped
// the allocator at ~128 and forced per-step L2 re-streaming (rounds 1-4).
template <int MODE>
__global__ __attribute__((amdgpu_flat_work_group_size(512, 512)))
__attribute__((amdgpu_waves_per_eu(2, 2))) void rec_kernel(
    const half_t* __restrict__ xg,     // [NB*NT,NG] fp16 (modes 0/1), biases folded
    const float* __restrict__ hT_in,   // [NB,NH]        (mode 2)
    const float* __restrict__ WihD,    // [NG,NH] fp32   (mode 2)
    const float* __restrict__ bih, const float* __restrict__ bhh,  // (mode 2)
    const half_t* __restrict__ Whh,    // [NG,NH] fp16
    half_t* __restrict__ seq_out,      // [NB,NT,NH] fp16 (modes 0/2)
    float* __restrict__ hT_out)        // [NB,NH]         (mode 1)
{
  const int b = blockIdx.x;
  const int tid = threadIdx.x;
  const int j = tid >> 2;
  const int kq = tid & 3;

  // h double-buffer: quarters padded to 48 halfs (96 B) -> bases on banks
  // {0,24,16,8}; uniform-address broadcast b128 reads, conflict-free.
  __shared__ __align__(16) half_t hbuf[2][4][48];
  __shared__ __align__(16) half_t xgs[2][8][NG];  // 8-step xg double buffer (modes 0/1)
  __shared__ float xgc[NG];                       // const xg (mode 2)
  __shared__ float hinf[NH];

  // Resident recurrent weights: 4 gates x 32 k = 16 x f16x8 (64 VGPRs), pinned.
  f16x8 wh8[4][4];
#pragma unroll
  for (int gi = 0; gi < 4; ++gi) {
    const f16x8* p = reinterpret_cast<const f16x8*>(Whh + (size_t)(gi * NH + j) * NH + kq * 32);
#pragma unroll
    for (int r = 0; r < 4; ++r) wh8[gi][r] = p[r];
  }
#pragma unroll
  for (int gi = 0; gi < 4; ++gi)
#pragma unroll
    for (int r = 0; r < 4; ++r) pinv8(wh8[gi][r]);

  if (tid < NH) hbuf[0][tid >> 5][tid & 31] = (half_t)0.0f;  // h0 = 0
  float c = 0.0f;                                            // c0 (replicated x4 kq lanes)

  if (MODE == 2) {
    // one-time: xgc[g] = bih+bhh + Wih[g,:].hT[b,:]  (fp32, thread = gate)
    if (tid < NH) hinf[tid] = hT_in[(size_t)b * NH + tid];
    __syncthreads();
    float a0 = bih[tid] + bhh[tid], a1 = 0.f, a2 = 0.f, a3 = 0.f;
    const float4* wr = (const float4*)(WihD + (size_t)tid * NH);
    const float4* hv = (const float4*)hinf;
#pragma unroll
    for (int k = 0; k < 8; ++k) {
      a0 = dot4(wr[4 * k + 0], hv[4 * k + 0], a0);
      a1 = dot4(wr[4 * k + 1], hv[4 * k + 1], a1);
      a2 = dot4(wr[4 * k + 2], hv[4 * k + 2], a2);
      a3 = dot4(wr[4 * k + 3], hv[4 * k + 3], a3);
    }
    xgc[tid] = (a0 + a1) + (a2 + a3);
    __syncthreads();
  }

  half_t g[8];
  const half_t* xrow = nullptr;
  if (MODE != 2) {
    xrow = xg + (size_t)b * NT * NG + tid;  // thread = gate column
#pragma unroll
    for (int s = 0; s < 8; ++s) g[s] = xrow[(size_t)s * NG];  // chunk 0
  }

  for (int ch = 0; ch < NT / 8; ++ch) {
    if (MODE != 2) {
      // commit staged chunk to LDS; issue loads for next chunk (hidden under 8 steps)
#pragma unroll
      for (int s = 0; s < 8; ++s) xgs[ch & 1][s][tid] = g[s];
      if (ch < NT / 8 - 1) {
#pragma unroll
        for (int s = 0; s < 8; ++s) g[s] = xrow[(size_t)((ch + 1) * 8 + s) * NG];
      }
      __syncthreads();
    }

#pragma unroll 1
    for (int tt = 0; tt < 8; ++tt) {
      const int t = ch * 8 + tt;
      const int p = t & 1;

      float a0 = 0.f, a1 = 0.f, a2 = 0.f, a3 = 0.f;
      const f16x8* hv8 = reinterpret_cast<const f16x8*>(&hbuf[p][kq][0]);
#pragma unroll
      for (int r8 = 0; r8 < 4; ++r8) {
        const f16x8 H = hv8[r8];
        const half2_t h0 = lo2(H, 0), h1 = lo2(H, 1), h2 = lo2(H, 2), h3 = lo2(H, 3);
        {
          const f16x8 W = wh8[0][r8];
          const half2_t w0 = lo2(W, 0), w1 = lo2(W, 1), w2 = lo2(W, 2), w3 = lo2(W, 3);
          a0 = fdot2(w0, h0, a0); a0 = fdot2(w1, h1, a0);
          a0 = fdot2(w2, h2, a0); a0 = fdot2(w3, h3, a0);
        }
        {
          const f16x8 W = wh8[1][r8];
          const half2_t w0 = lo2(W, 0), w1 = lo2(W, 1), w2 = lo2(W, 2), w3 = lo2(W, 3);
          a1 = fdot2(w0, h0, a1); a1 = fdot2(w1, h1, a1);
          a1 = fdot2(w2, h2, a1); a1 = fdot2(w3, h3, a1);
        }
        {
          const f16x8 W = wh8[2][r8];
          const half2_t w0 = lo2(W, 0), w1 = lo2(W, 1), w2 = lo2(W, 2), w3 = lo2(W, 3);
          a2 = fdot2(w0, h0, a2); a2 = fdot2(w1, h1, a2);
          a2 = fdot2(w2, h2, a2); a2 = fdot2(w3, h3, a2);
        }
        {
          const f16x8 W = wh8[3][r8];
          const half2_t w0 = lo2(W, 0), w1 = lo2(W, 1), w2 = lo2(W, 2), w3 = lo2(W, 3);
          a3 = fdot2(w0, h0, a3); a3 = fdot2(w1, h1, a3);
          a3 = fdot2(w2, h2, a3); a3 = fdot2(w3, h3, a3);
        }
      }
      a0 += __shfl_xor(a0, 1, 4); a0 += __shfl_xor(a0, 2, 4);
      a1 += __shfl_xor(a1, 1, 4); a1 += __shfl_xor(a1, 2, 4);
      a2 += __shfl_xor(a2, 1, 4); a2 += __shfl_xor(a2, 2, 4);
      a3 += __shfl_xor(a3, 1, 4); a3 += __shfl_xor(a3, 2, 4);

      float xi, xf, xgg, xo;
      if (MODE == 2) {
        xi = xgc[j]; xf = xgc[j + 128]; xgg = xgc[j + 256]; xo = xgc[j + 384];
      } else {
        const half_t* xb = &xgs[ch & 1][tt][0];
        xi = (float)xb[j]; xf = (float)xb[j + 128];
        xgg = (float)xb[j + 256]; xo = (float)xb[j + 384];
      }

      const float ig = sigm(a0 + xi);
      const float fg = sigm(a1 + xf);
      const float gg = tanh_(a2 + xgg);
      const float og = sigm(a3 + xo);
      c = fmaf(fg, c, ig * gg);
      const float h = og * tanh_(c);

      if (kq == 0) {
        hbuf[p ^ 1][j >> 5][j & 31] = (half_t)h;
        if (MODE != 1) seq_out[((size_t)b * NT + t) * NH + j] = (half_t)h;
        else if (t == NT - 1) hT_out[(size_t)b * NH + j] = h;
      }
      __syncthreads();
    }
  }
}

}  // namespace

extern "C" void kernel_launch(void* const* d_in, const int* in_sizes, int n_in,
                              void* d_out, int out_size, void* d_ws, size_t ws_size,
                              hipStream_t stream) {
  (void)in_sizes; (void)n_in; (void)out_size; (void)ws_size;

  const float* x     = (const float*)d_in[0];
  const float* e0Wih = (const float*)d_in[1];
  const float* e0Whh = (const float*)d_in[2];
  const float* e0bih = (const float*)d_in[3];
  const float* e0bhh = (const float*)d_in[4];
  const float* e1Wih = (const float*)d_in[5];
  const float* e1Whh = (const float*)d_in[6];
  const float* e1bih = (const float*)d_in[7];
  const float* e1bhh = (const float*)d_in[8];
  const float* d0Wih = (const float*)d_in[9];
  const float* d0Whh = (const float*)d_in[10];
  const float* d0bih = (const float*)d_in[11];
  const float* d0bhh = (const float*)d_in[12];
  const float* d1Wih = (const float*)d_in[13];
  const float* d1Whh = (const float*)d_in[14];
  const float* d1bih = (const float*)d_in[15];
  const float* d1bhh = (const float*)d_in[16];
  const float* Wout  = (const float*)d_in[17];
  const float* bout  = (const float*)d_in[18];
  float* out = (float*)d_out;

  // ---- workspace: Whh fp16 x4 | seqA fp16 [B*T,128] | xg fp16 [B*T,512] | hT f32 ----
  half_t* whh0 = (half_t*)d_ws;
  half_t* whh1 = whh0 + 512 * 128;
  half_t* whh2 = whh1 + 512 * 128;
  half_t* whh3 = whh2 + 512 * 128;
  half_t* seqA = whh3 + 512 * 128;
  half_t* xgb  = seqA + (size_t)NB * NT * NH;
  float*  hT   = (float*)(xgb + (size_t)NB * NT * NG);

  cvt_kernel<<<64, 256, 0, stream>>>(e0Whh, whh0, 512 * 128 / 4);
  cvt_kernel<<<64, 256, 0, stream>>>(e1Whh, whh1, 512 * 128 / 4);
  cvt_kernel<<<64, 256, 0, stream>>>(d0Whh, whh2, 512 * 128 / 4);
  cvt_kernel<<<64, 256, 0, stream>>>(d1Whh, whh3, 512 * 128 / 4);

  const int M = NB * NT;  // 131072
  dim3 gX(M / 128, NG / 64), gP(M / 128, 1), blkG(256);
  dim3 gR(NB), blkR(512);

  // enc0: xg0 = x @ e0Wih^T + b   (A fp32, K=64) -> rec -> seqA
  xg_gemm<64, true, false><<<gX, blkG, 0, stream>>>(x, e0Wih, e0bih, e0bhh, xgb, nullptr, NG);
  rec_kernel<0><<<gR, blkR, 0, stream>>>(xgb, nullptr, nullptr, nullptr, nullptr, whh0, seqA, nullptr);

  // enc1: xg1 = seqA @ e1Wih^T + b (A fp16, K=128) -> rec -> hT
  xg_gemm<128, false, false><<<gX, blkG, 0, stream>>>(seqA, e1Wih, e1bih, e1bhh, xgb, nullptr, NG);
  rec_kernel<1><<<gR, blkR, 0, stream>>>(xgb, nullptr, nullptr, nullptr, nullptr, whh1, nullptr, hT);

  // dec0: const xg from hT -> rec -> seqA
  rec_kernel<2><<<gR, blkR, 0, stream>>>(nullptr, hT, d0Wih, d0bih, d0bhh, whh2, seqA, nullptr);

  // dec1: xg3 = seqA @ d1Wih^T + b -> rec -> seqA (h-seq)
  xg_gemm<128, false, false><<<gX, blkG, 0, stream>>>(seqA, d1Wih, d1bih, d1bhh, xgb, nullptr, NG);
  rec_kernel<0><<<gR, blkR, 0, stream>>>(xgb, nullptr, nullptr, nullptr, nullptr, whh3, seqA, nullptr);

  // projection: out = seqA @ Wout^T + bout (fp32 out, N=64)
  xg_gemm<128, false, true><<<gP, blkG, 0, stream>>>(seqA, Wout, bout, nullptr, nullptr, out, 64);
}